// Round 12
// baseline (645.558 us; speedup 1.0000x reference)
//
#include <hip/hip_runtime.h>
#include <math.h>

#define BN    8
#define NN    2048
#define NP1   2049
#define VSTR  2056   // padded a/b vector stride (floats), 16B-aligned rows
#define DD    256
#define NITER 20
#define NBLK  256    // persistent grid size, 1 block/CU
#define GRP   32     // blocks per batch (independent barrier group)

typedef float f32x2 __attribute__((ext_vector_type(2)));

// ws layout: a[BN*VSTR] f32 | b[BN*VSTR] f32 | sums[41*BN] f32 | bar[BN*GRP] i32 |
//            psum[2*BN*GRP] f32 | K8[BN*NN*NN] fp8

__global__ void init_kernel(float* __restrict__ bvec, int nb, float* __restrict__ sums,
                            int* __restrict__ bar) {
    int tid = blockIdx.x * blockDim.x + threadIdx.x;
    int stride = gridDim.x * blockDim.x;
    for (int i = tid; i < nb; i += stride) bvec[i] = 1.0f;            // v0 = 0 -> b = 1
    for (int i = tid; i < 41 * BN; i += stride) sums[i] = (i < BN) ? (float)NN : 0.0f;
    if (tid < BN * GRP) bar[tid] = 0;
}

// K = exp(F^T F / 16), diag = 0. FP8 variant packs 4 cols -> u32 (OCP e4m3 HW cvt)
// into K8 (stride NN); fp32 variant writes into out's NxN (stride NP1). tj>=ti only.
template <bool FP8>
__global__ __launch_bounds__(256) void build_k_kernel(const float* __restrict__ F,
                                                      float* __restrict__ out,
                                                      unsigned char* __restrict__ K8) {
    int ti = blockIdx.x, tj = blockIdx.y, bb = blockIdx.z;
    if (tj < ti) return;
    __shared__ float As[32][64];
    __shared__ float Bs[32][64];
    int t  = threadIdx.x;
    int tx = t & 15, ty = t >> 4;
    float acc[4][4] = {};
    const float* Fb = F + (size_t)bb * DD * NN;
    int i0 = ti * 64, j0 = tj * 64;
    for (int k0 = 0; k0 < DD; k0 += 32) {
#pragma unroll
        for (int v = 0; v < 2; v++) {
            int f = t + 256 * v;
            int row = f >> 4, c4 = (f & 15) * 4;
            *(float4*)&As[row][c4] = *(const float4*)&Fb[(size_t)(k0 + row) * NN + i0 + c4];
            *(float4*)&Bs[row][c4] = *(const float4*)&Fb[(size_t)(k0 + row) * NN + j0 + c4];
        }
        __syncthreads();
#pragma unroll
        for (int k = 0; k < 32; k++) {
            float4 av = *(float4*)&As[k][ty * 4];
            float4 bv = *(float4*)&Bs[k][tx * 4];
            float ar[4] = {av.x, av.y, av.z, av.w};
            float br[4] = {bv.x, bv.y, bv.z, bv.w};
#pragma unroll
            for (int r = 0; r < 4; r++)
#pragma unroll
                for (int c = 0; c < 4; c++)
                    acc[r][c] = fmaf(ar[r], br[c], acc[r][c]);
        }
        __syncthreads();
    }
#pragma unroll
    for (int r = 0; r < 4; r++) {
        int i = i0 + ty * 4 + r;
        float kvl[4];
#pragma unroll
        for (int c = 0; c < 4; c++) {
            int j = j0 + tx * 4 + c;
            kvl[c] = (i == j) ? 0.0f : __expf(acc[r][c] * 0.0625f);  // 1/sqrt(256)
        }
        if constexpr (FP8) {
            unsigned w = __builtin_amdgcn_cvt_pk_fp8_f32(kvl[0], kvl[1], 0, false);
            w = __builtin_amdgcn_cvt_pk_fp8_f32(kvl[2], kvl[3], w, true);
            unsigned char* K8b = K8 + (size_t)bb * NN * NN;
            *(unsigned*)(K8b + (size_t)i * NN + (j0 + tx * 4)) = w;
            if (tj > ti) {
#pragma unroll
                for (int c = 0; c < 4; c++)
                    K8b[(size_t)(j0 + tx * 4 + c) * NN + i] =
                        (unsigned char)((w >> (8 * c)) & 0xff);
            }
        } else {
            float* outb = out + (size_t)bb * NP1 * NP1;
#pragma unroll
            for (int c = 0; c < 4; c++) {
                int j = j0 + tx * 4 + c;
                outb[(size_t)i * NP1 + j] = kvl[c];
                if (tj > ti) outb[(size_t)j * NP1 + i] = kvl[c];
            }
        }
    }
}

// Persistent Sinkhorn, 128 KB fp8 K-shard in LDS. R11 post-mortem: sync
// PRIMITIVE changes (RMW chain -> store+poll) were neutral; the ~6 us/pass
// residual is cross-XCD propagation on the serial chain (x visibility, flag
// propagation, acquire-invalidate, cold x re-read) because batch blocks were
// scattered round-robin over all 8 XCDs. This round: batch <-> XCD
// co-location — batch = blk & 7 (XCD id under round-robin dispatch),
// rb = blk >> 3 — so each batch's x vector, barrier line, and psum line stay
// in ONE XCD's L2. Agent-scope ops kept: correctness placement-independent.
// 256 blocks x 1024 threads = 1 block/CU. Thread: row=tid>>4 (of 64-row
// shard), cols [(tid&15)*128,+128). K-shard XOR-swizzled (bits[6:4]^=seg&7).
__global__ __launch_bounds__(1024) void sink_persist(const unsigned char* __restrict__ K8,
                                                     float* __restrict__ avec,
                                                     float* __restrict__ bvec,
                                                     int* __restrict__ bar,
                                                     float* __restrict__ psum,
                                                     const float* __restrict__ alpha) {
    int blk   = blockIdx.x;
    int batch = blk & 7;           // XCD id under round-robin dispatch
    int rb    = blk >> 3;
    int tid   = threadIdx.x;
    int seg   = tid & 15;
    int row   = tid >> 4;          // row within the 64-row shard
    int grow  = rb * 64 + row;     // global row

    __shared__ __align__(16) unsigned char Ks[64 * 2048];   // 128 KB fp8 shard
    __shared__ float xs[16 * 132];                          // padded x stage
    __shared__ float wsum[16];
    __shared__ float stot;

    // one-time stage: global (linear) -> LDS (swizzled), 128 B/thread x 8
    {
        const int4* gsrc = (const int4*)(K8 + ((size_t)batch * NN + (size_t)rb * 64) * NN);
#pragma unroll
        for (int q = 0; q < 8; q++) {
            int idx = q * 1024 + tid;
            int4 v = gsrc[idx];
            int g = idx * 16;
            int r_ = g >> 11, bir = g & 2047;
            *(int4*)&Ks[r_ * 2048 + (bir ^ (((bir >> 7) & 7) << 4))] = v;
        }
    }   // first pass's __syncthreads() covers this staging

    float* av = avec + (size_t)batch * VSTR;
    float* bv = bvec + (size_t)batch * VSTR;
    int*   gbar = bar + batch * GRP;            // this batch's arrival slots (128 B line)
    float E    = __expf(alpha[0]);
    float binA = 0.f, binB = 1.0f;
    float S_in = 2048.0f;            // sum of vector entering current pass
    int   ep   = 0;                  // pass generation
    const float4* xp4 = (const float4*)(xs + seg * 132);
    const int kbase = row * 2048;
    const int sb    = seg * 128;
    const int sx    = (seg & 7) << 4;

#define MAC16(KI, ACC)                                                          \
    {                                                                           \
        int4 kv = *(const int4*)&Ks[kbase + ((sb + (KI) * 16) ^ sx)];           \
        float4 xa = xp4[(KI) * 4 + 0], xb = xp4[(KI) * 4 + 1];                  \
        float4 xc = xp4[(KI) * 4 + 2], xd = xp4[(KI) * 4 + 3];                  \
        f32x2 p0 = __builtin_amdgcn_cvt_pk_f32_fp8(kv.x, false);                \
        f32x2 p1 = __builtin_amdgcn_cvt_pk_f32_fp8(kv.x, true);                 \
        f32x2 p2 = __builtin_amdgcn_cvt_pk_f32_fp8(kv.y, false);                \
        f32x2 p3 = __builtin_amdgcn_cvt_pk_f32_fp8(kv.y, true);                 \
        f32x2 p4 = __builtin_amdgcn_cvt_pk_f32_fp8(kv.z, false);                \
        f32x2 p5 = __builtin_amdgcn_cvt_pk_f32_fp8(kv.z, true);                 \
        f32x2 p6 = __builtin_amdgcn_cvt_pk_f32_fp8(kv.w, false);                \
        f32x2 p7 = __builtin_amdgcn_cvt_pk_f32_fp8(kv.w, true);                 \
        ACC = fmaf(p0.x, xa.x, ACC); ACC = fmaf(p0.y, xa.y, ACC);               \
        ACC = fmaf(p1.x, xa.z, ACC); ACC = fmaf(p1.y, xa.w, ACC);               \
        ACC = fmaf(p2.x, xb.x, ACC); ACC = fmaf(p2.y, xb.y, ACC);               \
        ACC = fmaf(p3.x, xb.z, ACC); ACC = fmaf(p3.y, xb.w, ACC);               \
        ACC = fmaf(p4.x, xc.x, ACC); ACC = fmaf(p4.y, xc.y, ACC);               \
        ACC = fmaf(p5.x, xc.z, ACC); ACC = fmaf(p5.y, xc.w, ACC);               \
        ACC = fmaf(p6.x, xd.x, ACC); ACC = fmaf(p6.y, xd.y, ACC);               \
        ACC = fmaf(p7.x, xd.z, ACC); ACC = fmaf(p7.y, xd.w, ACC);               \
    }

#define SINK_PASS(XIN, XOUT, BIN_IN, BIN_OUT, P, LAST)                          \
    {                                                                           \
        {   /* stage XIN[0..2048) into LDS (coalesced float2) */                \
            float2 v = ((const float2*)(XIN))[tid];                             \
            int j = tid * 2;                                                    \
            float* d = xs + ((j >> 7) * 132 + (j & 127));                       \
            d[0] = v.x; d[1] = v.y;                                             \
        }                                                                       \
        __syncthreads();                                                        \
        float dot0 = 0.f, dot1 = 0.f;                                           \
        MAC16(0, dot0) MAC16(1, dot1) MAC16(2, dot0) MAC16(3, dot1)             \
        MAC16(4, dot0) MAC16(5, dot1) MAC16(6, dot0) MAC16(7, dot1)             \
        float dot = dot0 + dot1;                                                \
        dot += __shfl_xor(dot, 1);                                              \
        dot += __shfl_xor(dot, 2);                                              \
        dot += __shfl_xor(dot, 4);                                              \
        dot += __shfl_xor(dot, 8);                                              \
        float val = (1.0f / 4096.0f) / (dot + E * (BIN_IN));                    \
        BIN_OUT = 0.5f / (E * (S_in + (BIN_IN)));                               \
        float ys = val;                                                         \
        ys += __shfl_xor(ys, 16);                                               \
        ys += __shfl_xor(ys, 32);                                               \
        if ((tid & 15) == 0) (XOUT)[grow] = val;                                \
        if ((tid & 63) == 0) wsum[tid >> 6] = ys;                               \
        __syncthreads();   /* all block stores drained (vmcnt) at barrier */    \
        if (!(LAST)) {                                                          \
            ep++;                                                               \
            float* pp = psum + (((P) & 1) * BN + batch) * GRP;                  \
            if (tid == 0) {                                                     \
                float s = 0.f;                                                  \
                _Pragma("unroll")                                               \
                for (int w = 0; w < 16; w++) s += wsum[w];                      \
                __hip_atomic_store(&pp[rb], s, __ATOMIC_RELAXED,                \
                                   __HIP_MEMORY_SCOPE_AGENT);                   \
                __builtin_amdgcn_fence(__ATOMIC_RELEASE, "agent");              \
                __hip_atomic_store(&gbar[rb], ep, __ATOMIC_RELAXED,             \
                                   __HIP_MEMORY_SCOPE_AGENT);                   \
            }                                                                   \
            if (tid < GRP) {                                                    \
                while (__hip_atomic_load(&gbar[tid], __ATOMIC_RELAXED,          \
                                         __HIP_MEMORY_SCOPE_AGENT) < ep)        \
                    __builtin_amdgcn_s_sleep(1);                                \
            }                                                                   \
            if (tid < 64) {                                                     \
                __builtin_amdgcn_fence(__ATOMIC_ACQUIRE, "agent");              \
                float ps = 0.f;                                                 \
                if (tid < GRP)                                                  \
                    ps = __hip_atomic_load(&pp[tid], __ATOMIC_RELAXED,          \
                                           __HIP_MEMORY_SCOPE_AGENT);           \
                ps += __shfl_xor(ps, 1);                                        \
                ps += __shfl_xor(ps, 2);                                        \
                ps += __shfl_xor(ps, 4);                                        \
                ps += __shfl_xor(ps, 8);                                        \
                ps += __shfl_xor(ps, 16);                                       \
                if (tid == 0) stot = ps;                                        \
            }                                                                   \
            __syncthreads();                                                    \
            S_in = stot;                                                        \
        }                                                                       \
    }

    for (int it2 = 0; it2 < NITER; it2++) {
        int p = 2 * it2 + 1;
        SINK_PASS(bv, av, binB, binA, p, false);
        SINK_PASS(av, bv, binA, binB, p + 1, (it2 == NITER - 1));
    }
#undef SINK_PASS
#undef MAC16

    if (tid == 0) { av[NN] = binA; bv[NN] = binB; }
}

// fp32 fallback pass (K in d_out, stride NP1) for ws-too-small case.
__global__ __launch_bounds__(256) void sink_pass_f32(const float* __restrict__ K,
                                                     const float* __restrict__ xin,
                                                     float* __restrict__ xout,
                                                     const float* __restrict__ sum_in,
                                                     float* __restrict__ sum_out,
                                                     const float* __restrict__ alpha) {
    int bb = blockIdx.y;
    int i0 = blockIdx.x * 16;
    __shared__ float xsl[NN];
    __shared__ float rowa[16];
    const float* xinb = xin + (size_t)bb * VSTR;
    int t = threadIdx.x;
    for (int j = t; j < NN; j += 256) xsl[j] = xinb[j];
    __syncthreads();
    float E  = __expf(alpha[0]);
    float xN = xinb[NN];
    int wave = t >> 6, lane = t & 63;
    const float* Kb = K + (size_t)bb * NP1 * NP1;
    for (int r = wave; r < 16; r += 4) {
        int i = i0 + r;
        const float* rowp = Kb + (size_t)i * NP1;
        float acc = 0.f;
        for (int j = lane; j < NN; j += 64) acc = fmaf(rowp[j], xsl[j], acc);
#pragma unroll
        for (int off = 32; off >= 1; off >>= 1) acc += __shfl_xor(acc, off);
        if (lane == 0) {
            float v = (1.0f / 4096.0f) / (acc + E * xN);
            xout[(size_t)bb * VSTR + i] = v;
            rowa[r] = v;
        }
    }
    __syncthreads();
    if (t == 0) {
        float s = 0.f;
#pragma unroll
        for (int r = 0; r < 16; r++) s += rowa[r];
        atomicAdd(sum_out + bb, s);
        if (blockIdx.x == 0) xout[(size_t)bb * VSTR + NN] = 0.5f / (E * (sum_in[bb] + xN));
    }
}

// out[i,j] = K*a_i*b_j*4096*cost (i,j<N), bins use E. FP8: K from K8; else in-place.
template <bool FP8>
__global__ __launch_bounds__(256) void final_kernel(float* __restrict__ out,
                                                    const unsigned char* __restrict__ K8,
                                                    const float* __restrict__ avec,
                                                    const float* __restrict__ bvec,
                                                    const float* __restrict__ pos,
                                                    const float* __restrict__ alpha) {
    int bb = blockIdx.y;
    int i0 = blockIdx.x * 16;
    __shared__ float as_[16], ys[16], xs2[16];
    int t = threadIdx.x;
    if (t < 16) {
        int i = i0 + t;
        as_[t] = (i < NP1) ? avec[(size_t)bb * VSTR + i] : 0.f;
        if (i < NN) {
            ys[t]  = pos[((size_t)bb * NN + i) * 2 + 0];
            xs2[t] = pos[((size_t)bb * NN + i) * 2 + 1];
        } else {
            ys[t] = 1e9f; xs2[t] = 1e9f;
        }
    }
    __syncthreads();
    float E = __expf(alpha[0]);
    float* outb = out + (size_t)bb * NP1 * NP1;
    const unsigned char* K8b = K8 + (size_t)bb * NN * NN;
    for (int j = t; j < NP1; j += 256) {
        float bj = bvec[(size_t)bb * VSTR + j];
        bool jin = (j < NN);
        float yj = 0.f, xj = 0.f;
        if (jin) {
            yj = pos[((size_t)bb * NN + j) * 2 + 0];
            xj = pos[((size_t)bb * NN + j) * 2 + 1];
        }
#pragma unroll 1
        for (int r = 0; r < 16; r++) {
            int i = i0 + r;
            if (i >= NP1) break;
            size_t idx = (size_t)i * NP1 + j;
            float v;
            if (i < NN && jin) {
                float Kv;
                if constexpr (FP8)
                    Kv = __builtin_amdgcn_cvt_f32_fp8((int)K8b[(size_t)i * NN + j], 0);
                else
                    Kv = outb[idx];
                bool c = (fabsf(ys[r] - yj) <= 0.1f) && (fabsf(xs2[r] - xj) <= 0.1f);
                v = c ? Kv * as_[r] * bj * 4096.0f : 0.0f;
            } else {
                v = E * as_[r] * bj * 4096.0f;
            }
            outb[idx] = v;
        }
    }
}

extern "C" void kernel_launch(void* const* d_in, const int* in_sizes, int n_in,
                              void* d_out, int out_size, void* d_ws, size_t ws_size,
                              hipStream_t stream) {
    const float* F     = (const float*)d_in[0];  // (B, D, N)
    const float* pos   = (const float*)d_in[1];  // (B, N, 2)
    const float* alpha = (const float*)d_in[3];  // (1,)
    float* out = (float*)d_out;
    float* ws  = (float*)d_ws;

    float* avec = ws;
    float* bvec = ws + BN * VSTR;
    float* sums = ws + 2 * BN * VSTR;                 // 41*BN floats (fallback path)
    int*   bar  = (int*)(sums + 41 * BN);             // BN x GRP arrival slots
    float* psum = (float*)(bar + BN * GRP);           // 2 x BN x GRP partial sums
    unsigned char* K8 = (unsigned char*)(psum + 2 * BN * GRP);  // 33.5 MB fp8

    size_t need = (size_t)(2 * BN * VSTR + 41 * BN + 3 * BN * GRP) * 4
                + (size_t)BN * NN * NN;
    bool fp8 = (ws_size >= need);

    hipLaunchKernelGGL(init_kernel, dim3(64), dim3(256), 0, stream, bvec, BN * VSTR,
                       sums, bar);

    if (fp8) {
        hipLaunchKernelGGL((build_k_kernel<true>), dim3(32, 32, BN), dim3(256), 0, stream,
                           F, out, K8);
        const unsigned char* Kp = K8;
        float* ap = avec; float* bp = bvec; int* brp = bar; float* pp = psum;
        const float* alp = alpha;
        void* params[6] = {(void*)&Kp, (void*)&ap, (void*)&bp, (void*)&brp,
                           (void*)&pp, (void*)&alp};
        hipLaunchCooperativeKernel((const void*)sink_persist, dim3(NBLK), dim3(1024),
                                   params, 0, stream);
        hipLaunchKernelGGL((final_kernel<true>), dim3((NP1 + 15) / 16, BN), dim3(256), 0,
                           stream, out, K8, avec, bvec, pos, alpha);
    } else {
        hipLaunchKernelGGL((build_k_kernel<false>), dim3(32, 32, BN), dim3(256), 0, stream,
                           F, out, K8);
        const float* xin = bvec;
        float* xout = avec;
        for (int p = 1; p <= 2 * NITER; p++) {
            hipLaunchKernelGGL(sink_pass_f32, dim3(NN / 16, BN), dim3(256), 0, stream,
                               out, xin, xout, sums + (p - 1) * BN, sums + p * BN, alpha);
            float* tmp = (float*)xin; xin = xout; xout = tmp;
        }
        hipLaunchKernelGGL((final_kernel<false>), dim3((NP1 + 15) / 16, BN), dim3(256), 0,
                           stream, out, K8, avec, bvec, pos, alpha);
    }
}

// Round 13
// 601.271 us; speedup vs baseline: 1.0737x; 1.0737x over previous
//
#include <hip/hip_runtime.h>
#include <math.h>

#define BN    8
#define NN    2048
#define NP1   2049
#define VSTR  2056   // padded a/b vector stride (floats), 16B-aligned rows
#define DD    256
#define NITER 20
#define NBLK  256    // persistent grid size, 1 block/CU
#define GRP   32     // blocks per batch (independent barrier group)

typedef float f32x2 __attribute__((ext_vector_type(2)));
typedef _Float16 half2_t __attribute__((ext_vector_type(2)));

// ws layout: a[BN*VSTR] f32 | b[BN*VSTR] f32 | sums[41*BN] f32 | bar[BN*GRP] i32 |
//            psum[2*BN*GRP] f32 | K8[BN*NN*NN] fp8

__global__ void init_kernel(float* __restrict__ bvec, int nb, float* __restrict__ sums,
                            int* __restrict__ bar) {
    int tid = blockIdx.x * blockDim.x + threadIdx.x;
    int stride = gridDim.x * blockDim.x;
    for (int i = tid; i < nb; i += stride) bvec[i] = 1.0f;            // v0 = 0 -> b = 1
    for (int i = tid; i < 41 * BN; i += stride) sums[i] = (i < BN) ? (float)NN : 0.0f;
    if (tid < BN * GRP) bar[tid] = 0;
}

// build_k v2 (fp8 path): K = exp(F^T F / 16), diag = 0. Full matrix (no mirror
// -> no byte-scatter writes, uniform 8 blocks/CU). 128x128 tile, 256 threads,
// 8x8 acc/thread, f16-pair LDS operands, v_dot2_f32_f16 inner (f32 accum).
// LDS layout As/Bs[k-pair][x] of half2 (pair = (F[2kp][x], F[2kp+1][x])).
__global__ __launch_bounds__(256) void build_k2(const float* __restrict__ F,
                                                unsigned char* __restrict__ K8) {
    int ti = blockIdx.x, tj = blockIdx.y, bb = blockIdx.z;
    __shared__ half2_t As[16][132];   // 16 k-pairs x 128 i (pad 4) = 8448 B
    __shared__ half2_t Bs[16][132];
    int t  = threadIdx.x;
    int tx = t & 15, ty = t >> 4;
    int i0 = ti * 128, j0 = tj * 128;
    const float* Fb = F + (size_t)bb * DD * NN;
    float acc[8][8] = {};

    for (int k0 = 0; k0 < DD; k0 += 32) {
#pragma unroll
        for (int q = 0; q < 2; q++) {
            int idx = t + 256 * q;          // 0..511
            int kp  = idx >> 5;             // 0..15
            int x4  = (idx & 31) * 4;       // 0..124
            const float* pa = Fb + (size_t)(k0 + 2 * kp) * NN + i0 + x4;
            float4 a0 = *(const float4*)pa;
            float4 a1 = *(const float4*)(pa + NN);
            half2_t pk[4];
            pk[0] = half2_t{(_Float16)a0.x, (_Float16)a1.x};
            pk[1] = half2_t{(_Float16)a0.y, (_Float16)a1.y};
            pk[2] = half2_t{(_Float16)a0.z, (_Float16)a1.z};
            pk[3] = half2_t{(_Float16)a0.w, (_Float16)a1.w};
            *(float4*)&As[kp][x4] = *(float4*)pk;
            const float* pb = Fb + (size_t)(k0 + 2 * kp) * NN + j0 + x4;
            float4 b0 = *(const float4*)pb;
            float4 b1 = *(const float4*)(pb + NN);
            pk[0] = half2_t{(_Float16)b0.x, (_Float16)b1.x};
            pk[1] = half2_t{(_Float16)b0.y, (_Float16)b1.y};
            pk[2] = half2_t{(_Float16)b0.z, (_Float16)b1.z};
            pk[3] = half2_t{(_Float16)b0.w, (_Float16)b1.w};
            *(float4*)&Bs[kp][x4] = *(float4*)pk;
        }
        __syncthreads();
#pragma unroll
        for (int kp = 0; kp < 16; kp++) {
            half2_t av[8], bv[8];
            *(float4*)&av[0] = *(float4*)&As[kp][ty * 8];
            *(float4*)&av[4] = *(float4*)&As[kp][ty * 8 + 4];
            *(float4*)&bv[0] = *(float4*)&Bs[kp][tx * 8];
            *(float4*)&bv[4] = *(float4*)&Bs[kp][tx * 8 + 4];
#pragma unroll
            for (int r = 0; r < 8; r++)
#pragma unroll
                for (int c = 0; c < 8; c++)
                    acc[r][c] = __builtin_amdgcn_fdot2(av[r], bv[c], acc[r][c], false);
        }
        __syncthreads();
    }

    unsigned char* K8b = K8 + (size_t)bb * NN * NN;
    bool diag = (ti == tj) && (ty == tx);
#pragma unroll
    for (int r = 0; r < 8; r++) {
        int i = i0 + ty * 8 + r;
        float kv[8];
#pragma unroll
        for (int c = 0; c < 8; c++) {
            float v = __expf(acc[r][c] * 0.0625f);     // scale 1/sqrt(256)/16
            if (diag && r == c) v = 0.0f;
            kv[c] = v;
        }
        unsigned w0 = __builtin_amdgcn_cvt_pk_fp8_f32(kv[0], kv[1], 0, false);
        w0 = __builtin_amdgcn_cvt_pk_fp8_f32(kv[2], kv[3], w0, true);
        unsigned w1 = __builtin_amdgcn_cvt_pk_fp8_f32(kv[4], kv[5], 0, false);
        w1 = __builtin_amdgcn_cvt_pk_fp8_f32(kv[6], kv[7], w1, true);
        uint2 wv; wv.x = w0; wv.y = w1;
        *(uint2*)(K8b + (size_t)i * NN + j0 + tx * 8) = wv;
    }
}

// fp32 fallback build (writes into out, stride NP1). Symmetric-half as before.
__global__ __launch_bounds__(256) void build_k_f32(const float* __restrict__ F,
                                                   float* __restrict__ out) {
    int ti = blockIdx.x, tj = blockIdx.y, bb = blockIdx.z;
    if (tj < ti) return;
    __shared__ float As[32][64];
    __shared__ float Bs[32][64];
    int t  = threadIdx.x;
    int tx = t & 15, ty = t >> 4;
    float acc[4][4] = {};
    const float* Fb = F + (size_t)bb * DD * NN;
    int i0 = ti * 64, j0 = tj * 64;
    for (int k0 = 0; k0 < DD; k0 += 32) {
#pragma unroll
        for (int v = 0; v < 2; v++) {
            int f = t + 256 * v;
            int row = f >> 4, c4 = (f & 15) * 4;
            *(float4*)&As[row][c4] = *(const float4*)&Fb[(size_t)(k0 + row) * NN + i0 + c4];
            *(float4*)&Bs[row][c4] = *(const float4*)&Fb[(size_t)(k0 + row) * NN + j0 + c4];
        }
        __syncthreads();
#pragma unroll
        for (int k = 0; k < 32; k++) {
            float4 av = *(float4*)&As[k][ty * 4];
            float4 bv = *(float4*)&Bs[k][tx * 4];
            float ar[4] = {av.x, av.y, av.z, av.w};
            float br[4] = {bv.x, bv.y, bv.z, bv.w};
#pragma unroll
            for (int r = 0; r < 4; r++)
#pragma unroll
                for (int c = 0; c < 4; c++)
                    acc[r][c] = fmaf(ar[r], br[c], acc[r][c]);
        }
        __syncthreads();
    }
#pragma unroll
    for (int r = 0; r < 4; r++) {
        int i = i0 + ty * 4 + r;
#pragma unroll
        for (int c = 0; c < 4; c++) {
            int j = j0 + tx * 4 + c;
            float Kv = (i == j) ? 0.0f : __expf(acc[r][c] * 0.0625f);
            float* outb = out + (size_t)bb * NP1 * NP1;
            outb[(size_t)i * NP1 + j] = Kv;
            if (tj > ti) outb[(size_t)j * NP1 + i] = Kv;
        }
    }
}

// Persistent Sinkhorn, 128 KB fp8 K-shard in LDS — byte-identical to R12.
__global__ __launch_bounds__(1024) void sink_persist(const unsigned char* __restrict__ K8,
                                                     float* __restrict__ avec,
                                                     float* __restrict__ bvec,
                                                     int* __restrict__ bar,
                                                     float* __restrict__ psum,
                                                     const float* __restrict__ alpha) {
    int blk   = blockIdx.x;
    int batch = blk & 7;           // XCD id under round-robin dispatch
    int rb    = blk >> 3;
    int tid   = threadIdx.x;
    int seg   = tid & 15;
    int row   = tid >> 4;          // row within the 64-row shard
    int grow  = rb * 64 + row;     // global row

    __shared__ __align__(16) unsigned char Ks[64 * 2048];   // 128 KB fp8 shard
    __shared__ float xs[16 * 132];                          // padded x stage
    __shared__ float wsum[16];
    __shared__ float stot;

    {
        const int4* gsrc = (const int4*)(K8 + ((size_t)batch * NN + (size_t)rb * 64) * NN);
#pragma unroll
        for (int q = 0; q < 8; q++) {
            int idx = q * 1024 + tid;
            int4 v = gsrc[idx];
            int g = idx * 16;
            int r_ = g >> 11, bir = g & 2047;
            *(int4*)&Ks[r_ * 2048 + (bir ^ (((bir >> 7) & 7) << 4))] = v;
        }
    }   // first pass's __syncthreads() covers this staging

    float* av = avec + (size_t)batch * VSTR;
    float* bv = bvec + (size_t)batch * VSTR;
    int*   gbar = bar + batch * GRP;
    float E    = __expf(alpha[0]);
    float binA = 0.f, binB = 1.0f;
    float S_in = 2048.0f;
    int   ep   = 0;
    const float4* xp4 = (const float4*)(xs + seg * 132);
    const int kbase = row * 2048;
    const int sb    = seg * 128;
    const int sx    = (seg & 7) << 4;

#define MAC16(KI, ACC)                                                          \
    {                                                                           \
        int4 kv = *(const int4*)&Ks[kbase + ((sb + (KI) * 16) ^ sx)];           \
        float4 xa = xp4[(KI) * 4 + 0], xb = xp4[(KI) * 4 + 1];                  \
        float4 xc = xp4[(KI) * 4 + 2], xd = xp4[(KI) * 4 + 3];                  \
        f32x2 p0 = __builtin_amdgcn_cvt_pk_f32_fp8(kv.x, false);                \
        f32x2 p1 = __builtin_amdgcn_cvt_pk_f32_fp8(kv.x, true);                 \
        f32x2 p2 = __builtin_amdgcn_cvt_pk_f32_fp8(kv.y, false);                \
        f32x2 p3 = __builtin_amdgcn_cvt_pk_f32_fp8(kv.y, true);                 \
        f32x2 p4 = __builtin_amdgcn_cvt_pk_f32_fp8(kv.z, false);                \
        f32x2 p5 = __builtin_amdgcn_cvt_pk_f32_fp8(kv.z, true);                 \
        f32x2 p6 = __builtin_amdgcn_cvt_pk_f32_fp8(kv.w, false);                \
        f32x2 p7 = __builtin_amdgcn_cvt_pk_f32_fp8(kv.w, true);                 \
        ACC = fmaf(p0.x, xa.x, ACC); ACC = fmaf(p0.y, xa.y, ACC);               \
        ACC = fmaf(p1.x, xa.z, ACC); ACC = fmaf(p1.y, xa.w, ACC);               \
        ACC = fmaf(p2.x, xb.x, ACC); ACC = fmaf(p2.y, xb.y, ACC);               \
        ACC = fmaf(p3.x, xb.z, ACC); ACC = fmaf(p3.y, xb.w, ACC);               \
        ACC = fmaf(p4.x, xc.x, ACC); ACC = fmaf(p4.y, xc.y, ACC);               \
        ACC = fmaf(p5.x, xc.z, ACC); ACC = fmaf(p5.y, xc.w, ACC);               \
        ACC = fmaf(p6.x, xd.x, ACC); ACC = fmaf(p6.y, xd.y, ACC);               \
        ACC = fmaf(p7.x, xd.z, ACC); ACC = fmaf(p7.y, xd.w, ACC);               \
    }

#define SINK_PASS(XIN, XOUT, BIN_IN, BIN_OUT, P, LAST)                          \
    {                                                                           \
        {                                                                       \
            float2 v = ((const float2*)(XIN))[tid];                             \
            int j = tid * 2;                                                    \
            float* d = xs + ((j >> 7) * 132 + (j & 127));                       \
            d[0] = v.x; d[1] = v.y;                                             \
        }                                                                       \
        __syncthreads();                                                        \
        float dot0 = 0.f, dot1 = 0.f;                                           \
        MAC16(0, dot0) MAC16(1, dot1) MAC16(2, dot0) MAC16(3, dot1)             \
        MAC16(4, dot0) MAC16(5, dot1) MAC16(6, dot0) MAC16(7, dot1)             \
        float dot = dot0 + dot1;                                                \
        dot += __shfl_xor(dot, 1);                                              \
        dot += __shfl_xor(dot, 2);                                              \
        dot += __shfl_xor(dot, 4);                                              \
        dot += __shfl_xor(dot, 8);                                              \
        float val = (1.0f / 4096.0f) / (dot + E * (BIN_IN));                    \
        BIN_OUT = 0.5f / (E * (S_in + (BIN_IN)));                               \
        float ys = val;                                                         \
        ys += __shfl_xor(ys, 16);                                               \
        ys += __shfl_xor(ys, 32);                                               \
        if ((tid & 15) == 0) (XOUT)[grow] = val;                                \
        if ((tid & 63) == 0) wsum[tid >> 6] = ys;                               \
        __syncthreads();                                                        \
        if (!(LAST)) {                                                          \
            ep++;                                                               \
            float* pp = psum + (((P) & 1) * BN + batch) * GRP;                  \
            if (tid == 0) {                                                     \
                float s = 0.f;                                                  \
                _Pragma("unroll")                                               \
                for (int w = 0; w < 16; w++) s += wsum[w];                      \
                __hip_atomic_store(&pp[rb], s, __ATOMIC_RELAXED,                \
                                   __HIP_MEMORY_SCOPE_AGENT);                   \
                __builtin_amdgcn_fence(__ATOMIC_RELEASE, "agent");              \
                __hip_atomic_store(&gbar[rb], ep, __ATOMIC_RELAXED,             \
                                   __HIP_MEMORY_SCOPE_AGENT);                   \
            }                                                                   \
            if (tid < GRP) {                                                    \
                while (__hip_atomic_load(&gbar[tid], __ATOMIC_RELAXED,          \
                                         __HIP_MEMORY_SCOPE_AGENT) < ep)        \
                    __builtin_amdgcn_s_sleep(1);                                \
            }                                                                   \
            if (tid < 64) {                                                     \
                __builtin_amdgcn_fence(__ATOMIC_ACQUIRE, "agent");              \
                float ps = 0.f;                                                 \
                if (tid < GRP)                                                  \
                    ps = __hip_atomic_load(&pp[tid], __ATOMIC_RELAXED,          \
                                           __HIP_MEMORY_SCOPE_AGENT);           \
                ps += __shfl_xor(ps, 1);                                        \
                ps += __shfl_xor(ps, 2);                                        \
                ps += __shfl_xor(ps, 4);                                        \
                ps += __shfl_xor(ps, 8);                                        \
                ps += __shfl_xor(ps, 16);                                       \
                if (tid == 0) stot = ps;                                        \
            }                                                                   \
            __syncthreads();                                                    \
            S_in = stot;                                                        \
        }                                                                       \
    }

    for (int it2 = 0; it2 < NITER; it2++) {
        int p = 2 * it2 + 1;
        SINK_PASS(bv, av, binB, binA, p, false);
        SINK_PASS(av, bv, binA, binB, p + 1, (it2 == NITER - 1));
    }
#undef SINK_PASS
#undef MAC16

    if (tid == 0) { av[NN] = binA; bv[NN] = binB; }
}

// fp32 fallback pass (K in d_out, stride NP1) for ws-too-small case.
__global__ __launch_bounds__(256) void sink_pass_f32(const float* __restrict__ K,
                                                     const float* __restrict__ xin,
                                                     float* __restrict__ xout,
                                                     const float* __restrict__ sum_in,
                                                     float* __restrict__ sum_out,
                                                     const float* __restrict__ alpha) {
    int bb = blockIdx.y;
    int i0 = blockIdx.x * 16;
    __shared__ float xsl[NN];
    __shared__ float rowa[16];
    const float* xinb = xin + (size_t)bb * VSTR;
    int t = threadIdx.x;
    for (int j = t; j < NN; j += 256) xsl[j] = xinb[j];
    __syncthreads();
    float E  = __expf(alpha[0]);
    float xN = xinb[NN];
    int wave = t >> 6, lane = t & 63;
    const float* Kb = K + (size_t)bb * NP1 * NP1;
    for (int r = wave; r < 16; r += 4) {
        int i = i0 + r;
        const float* rowp = Kb + (size_t)i * NP1;
        float acc = 0.f;
        for (int j = lane; j < NN; j += 64) acc = fmaf(rowp[j], xsl[j], acc);
#pragma unroll
        for (int off = 32; off >= 1; off >>= 1) acc += __shfl_xor(acc, off);
        if (lane == 0) {
            float v = (1.0f / 4096.0f) / (acc + E * xN);
            xout[(size_t)bb * VSTR + i] = v;
            rowa[r] = v;
        }
    }
    __syncthreads();
    if (t == 0) {
        float s = 0.f;
#pragma unroll
        for (int r = 0; r < 16; r++) s += rowa[r];
        atomicAdd(sum_out + bb, s);
        if (blockIdx.x == 0) xout[(size_t)bb * VSTR + NN] = 0.5f / (E * (sum_in[bb] + xN));
    }
}

// out[i,j] = K*a_i*b_j*4096*cost (i,j<N), bins use E. FP8: K from K8; else in-place.
template <bool FP8>
__global__ __launch_bounds__(256) void final_kernel(float* __restrict__ out,
                                                    const unsigned char* __restrict__ K8,
                                                    const float* __restrict__ avec,
                                                    const float* __restrict__ bvec,
                                                    const float* __restrict__ pos,
                                                    const float* __restrict__ alpha) {
    int bb = blockIdx.y;
    int i0 = blockIdx.x * 16;
    __shared__ float as_[16], ys[16], xs2[16];
    int t = threadIdx.x;
    if (t < 16) {
        int i = i0 + t;
        as_[t] = (i < NP1) ? avec[(size_t)bb * VSTR + i] : 0.f;
        if (i < NN) {
            ys[t]  = pos[((size_t)bb * NN + i) * 2 + 0];
            xs2[t] = pos[((size_t)bb * NN + i) * 2 + 1];
        } else {
            ys[t] = 1e9f; xs2[t] = 1e9f;
        }
    }
    __syncthreads();
    float E = __expf(alpha[0]);
    float* outb = out + (size_t)bb * NP1 * NP1;
    const unsigned char* K8b = K8 + (size_t)bb * NN * NN;
    for (int j = t; j < NP1; j += 256) {
        float bj = bvec[(size_t)bb * VSTR + j];
        bool jin = (j < NN);
        float yj = 0.f, xj = 0.f;
        if (jin) {
            yj = pos[((size_t)bb * NN + j) * 2 + 0];
            xj = pos[((size_t)bb * NN + j) * 2 + 1];
        }
#pragma unroll 1
        for (int r = 0; r < 16; r++) {
            int i = i0 + r;
            if (i >= NP1) break;
            size_t idx = (size_t)i * NP1 + j;
            float v;
            if (i < NN && jin) {
                float Kv;
                if constexpr (FP8)
                    Kv = __builtin_amdgcn_cvt_f32_fp8((int)K8b[(size_t)i * NN + j], 0);
                else
                    Kv = outb[idx];
                bool c = (fabsf(ys[r] - yj) <= 0.1f) && (fabsf(xs2[r] - xj) <= 0.1f);
                v = c ? Kv * as_[r] * bj * 4096.0f : 0.0f;
            } else {
                v = E * as_[r] * bj * 4096.0f;
            }
            outb[idx] = v;
        }
    }
}

extern "C" void kernel_launch(void* const* d_in, const int* in_sizes, int n_in,
                              void* d_out, int out_size, void* d_ws, size_t ws_size,
                              hipStream_t stream) {
    const float* F     = (const float*)d_in[0];  // (B, D, N)
    const float* pos   = (const float*)d_in[1];  // (B, N, 2)
    const float* alpha = (const float*)d_in[3];  // (1,)
    float* out = (float*)d_out;
    float* ws  = (float*)d_ws;

    float* avec = ws;
    float* bvec = ws + BN * VSTR;
    float* sums = ws + 2 * BN * VSTR;                 // 41*BN floats (fallback path)
    int*   bar  = (int*)(sums + 41 * BN);             // BN x GRP arrival slots
    float* psum = (float*)(bar + BN * GRP);           // 2 x BN x GRP partial sums
    unsigned char* K8 = (unsigned char*)(psum + 2 * BN * GRP);  // 33.5 MB fp8

    size_t need = (size_t)(2 * BN * VSTR + 41 * BN + 3 * BN * GRP) * 4
                + (size_t)BN * NN * NN;
    bool fp8 = (ws_size >= need);

    hipLaunchKernelGGL(init_kernel, dim3(64), dim3(256), 0, stream, bvec, BN * VSTR,
                       sums, bar);

    if (fp8) {
        hipLaunchKernelGGL(build_k2, dim3(16, 16, BN), dim3(256), 0, stream, F, K8);
        const unsigned char* Kp = K8;
        float* ap = avec; float* bp = bvec; int* brp = bar; float* pp = psum;
        const float* alp = alpha;
        void* params[6] = {(void*)&Kp, (void*)&ap, (void*)&bp, (void*)&brp,
                           (void*)&pp, (void*)&alp};
        hipLaunchCooperativeKernel((const void*)sink_persist, dim3(NBLK), dim3(1024),
                                   params, 0, stream);
        hipLaunchKernelGGL((final_kernel<true>), dim3((NP1 + 15) / 16, BN), dim3(256), 0,
                           stream, out, K8, avec, bvec, pos, alpha);
    } else {
        hipLaunchKernelGGL(build_k_f32, dim3(32, 32, BN), dim3(256), 0, stream, F, out);
        const float* xin = bvec;
        float* xout = avec;
        for (int p = 1; p <= 2 * NITER; p++) {
            hipLaunchKernelGGL(sink_pass_f32, dim3(NN / 16, BN), dim3(256), 0, stream,
                               out, xin, xout, sums + (p - 1) * BN, sums + p * BN, alpha);
            float* tmp = (float*)xin; xin = xout; xout = tmp;
        }
        hipLaunchKernelGGL((final_kernel<false>), dim3((NP1 + 15) / 16, BN), dim3(256), 0,
                           stream, out, K8, avec, bvec, pos, alpha);
    }
}

// Round 14
// 515.480 us; speedup vs baseline: 1.2523x; 1.1664x over previous
//
#include <hip/hip_runtime.h>
#include <math.h>

#define BN    8
#define NN    2048
#define NP1   2049
#define VSTR  2056   // padded a/b vector stride (floats), 16B-aligned rows
#define DD    256
#define NITER 20
#define NBLK  256    // persistent grid size, 1 block/CU
#define GRP   32     // blocks per batch (independent barrier group)

typedef float f32x2 __attribute__((ext_vector_type(2)));
typedef float f32x4_t __attribute__((ext_vector_type(4)));
typedef short short8 __attribute__((ext_vector_type(8)));

// ws layout: a[BN*VSTR] f32 | b[BN*VSTR] f32 | sums[41*BN] f32 | bar[BN*GRP] i32 |
//            psum[2*BN*GRP] f32 | K8[BN*NN*NN] fp8

__global__ void init_kernel(float* __restrict__ bvec, int nb, float* __restrict__ sums,
                            int* __restrict__ bar) {
    int tid = blockIdx.x * blockDim.x + threadIdx.x;
    int stride = gridDim.x * blockDim.x;
    for (int i = tid; i < nb; i += stride) bvec[i] = 1.0f;            // v0 = 0 -> b = 1
    for (int i = tid; i < 41 * BN; i += stride) sums[i] = (i < BN) ? (float)NN : 0.0f;
    if (tid < BN * GRP) bar[tid] = 0;
}

__device__ __forceinline__ unsigned short f2bf(float f) {
    unsigned u = __builtin_bit_cast(unsigned, f);
    return (unsigned short)((u + 0x7fffu + ((u >> 16) & 1u)) >> 16);   // RNE
}

// build_k v3: MFMA bf16. K = exp(F^T F / 16), diag=0, fp8 out. 128x128 tile,
// 4 waves (2x2), each wave 4x4 frags of mfma_f32_16x16x32_bf16. F-slab staged
// f32->bf16 into x-major LDS [x][k] (stride 80B: frag read = 1 aligned
// ds_read_b128, banks balanced). Epilogue: exp -> cvt_pk_fp8 -> column-major
// LDS bounce (132B stride, conflict-free) -> coalesced row-major u32 stores.
// Frag maps: A/B lane: idx=l&15, k=(l>>4)*8+e; C/D: col=l&15, row=(l>>4)*4+reg.
__global__ __launch_bounds__(256) void build_k3(const float* __restrict__ F,
                                                unsigned char* __restrict__ K8) {
    int ti = blockIdx.x, tj = blockIdx.y, bb = blockIdx.z;
    int i0 = ti * 128, j0 = tj * 128;
    const float* Fb = F + (size_t)bb * DD * NN;

    __shared__ __align__(16) unsigned char Ab[128 * 80];   // [x][k] bf16, 80B rows
    __shared__ __align__(16) unsigned char Bb[128 * 80];
    __shared__ __align__(4)  unsigned char Cm[128 * 132];  // col-major fp8 [c][i]

    int t = threadIdx.x;
    int w = t >> 6, l = t & 63;
    int wr = w >> 1, wc = w & 1;           // wave grid 2x2 -> 64x64 per wave
    int g = l >> 4, c16 = l & 15;

    f32x4_t acc[4][4];
#pragma unroll
    for (int r = 0; r < 4; r++)
#pragma unroll
        for (int c = 0; c < 4; c++) acc[r][c] = (f32x4_t){0.f, 0.f, 0.f, 0.f};

    for (int k0 = 0; k0 < DD; k0 += 32) {
        // stage both slabs: 1024 assignments of (x, k4): 4 coalesced f32 loads
        // (consecutive x per lane) + one 8B LDS write of 4 bf16.
#pragma unroll
        for (int q = 0; q < 4; q++) {
            int idx = q * 256 + t;
            int x = idx & 127, k4 = (idx >> 7) * 4;
            unsigned long long pa = 0, pb = 0;
#pragma unroll
            for (int e = 0; e < 4; e++) {
                const float* rowp = Fb + (size_t)(k0 + k4 + e) * NN;
                pa |= (unsigned long long)f2bf(rowp[i0 + x]) << (16 * e);
                pb |= (unsigned long long)f2bf(rowp[j0 + x]) << (16 * e);
            }
            *(unsigned long long*)(Ab + x * 80 + k4 * 2) = pa;
            *(unsigned long long*)(Bb + x * 80 + k4 * 2) = pb;
        }
        __syncthreads();

        short8 af[4], bf_[4];
#pragma unroll
        for (int rf = 0; rf < 4; rf++)
            af[rf] = *(const short8*)(Ab + (wr * 64 + rf * 16 + c16) * 80 + g * 16);
#pragma unroll
        for (int cf = 0; cf < 4; cf++)
            bf_[cf] = *(const short8*)(Bb + (wc * 64 + cf * 16 + c16) * 80 + g * 16);
#pragma unroll
        for (int rf = 0; rf < 4; rf++)
#pragma unroll
            for (int cf = 0; cf < 4; cf++)
                acc[rf][cf] = __builtin_amdgcn_mfma_f32_16x16x32_bf16(
                    af[rf], bf_[cf], acc[rf][cf], 0, 0, 0);
        __syncthreads();
    }

    // epilogue: exp, diag-zero, pack 4 rows (same col) -> u32 -> col-major LDS
#pragma unroll
    for (int rf = 0; rf < 4; rf++) {
#pragma unroll
        for (int cf = 0; cf < 4; cf++) {
            int ib = wr * 64 + rf * 16 + g * 4;        // local row base (mult of 4)
            int jl = wc * 64 + cf * 16 + c16;          // local col
            float v[4];
#pragma unroll
            for (int r = 0; r < 4; r++) {
                float e = __expf(acc[rf][cf][r] * 0.0625f);   // 1/sqrt(256)
                if (i0 + ib + r == j0 + jl) e = 0.0f;
                v[r] = e;
            }
            unsigned wd = __builtin_amdgcn_cvt_pk_fp8_f32(v[0], v[1], 0, false);
            wd = __builtin_amdgcn_cvt_pk_fp8_f32(v[2], v[3], wd, true);
            *(unsigned*)(Cm + jl * 132 + ib) = wd;
        }
    }
    __syncthreads();

    // coalesced row-major store: thread t -> row t>>1, col-half t&1 (64 cols)
    unsigned char* K8b = K8 + (size_t)bb * NN * NN;
    int il = t >> 1, hh = t & 1;
    unsigned wrow[16];
#pragma unroll
    for (int cq = 0; cq < 16; cq++) {
        int cb = hh * 64 + cq * 4;
        unsigned b0 = Cm[(cb + 0) * 132 + il];
        unsigned b1 = Cm[(cb + 1) * 132 + il];
        unsigned b2 = Cm[(cb + 2) * 132 + il];
        unsigned b3 = Cm[(cb + 3) * 132 + il];
        wrow[cq] = b0 | (b1 << 8) | (b2 << 16) | (b3 << 24);
    }
    uint4* dst = (uint4*)(K8b + (size_t)(i0 + il) * NN + j0 + hh * 64);
#pragma unroll
    for (int qq = 0; qq < 4; qq++) {
        uint4 u; u.x = wrow[qq * 4]; u.y = wrow[qq * 4 + 1];
        u.z = wrow[qq * 4 + 2]; u.w = wrow[qq * 4 + 3];
        dst[qq] = u;
    }
}

// fp32 fallback build (writes into out, stride NP1). Symmetric-half as before.
__global__ __launch_bounds__(256) void build_k_f32(const float* __restrict__ F,
                                                   float* __restrict__ out) {
    int ti = blockIdx.x, tj = blockIdx.y, bb = blockIdx.z;
    if (tj < ti) return;
    __shared__ float As[32][64];
    __shared__ float Bs[32][64];
    int t  = threadIdx.x;
    int tx = t & 15, ty = t >> 4;
    float acc[4][4] = {};
    const float* Fb = F + (size_t)bb * DD * NN;
    int i0 = ti * 64, j0 = tj * 64;
    for (int k0 = 0; k0 < DD; k0 += 32) {
#pragma unroll
        for (int v = 0; v < 2; v++) {
            int f = t + 256 * v;
            int row = f >> 4, c4 = (f & 15) * 4;
            *(float4*)&As[row][c4] = *(const float4*)&Fb[(size_t)(k0 + row) * NN + i0 + c4];
            *(float4*)&Bs[row][c4] = *(const float4*)&Fb[(size_t)(k0 + row) * NN + j0 + c4];
        }
        __syncthreads();
#pragma unroll
        for (int k = 0; k < 32; k++) {
            float4 av = *(float4*)&As[k][ty * 4];
            float4 bv = *(float4*)&Bs[k][tx * 4];
            float ar[4] = {av.x, av.y, av.z, av.w};
            float br[4] = {bv.x, bv.y, bv.z, bv.w};
#pragma unroll
            for (int r = 0; r < 4; r++)
#pragma unroll
                for (int c = 0; c < 4; c++)
                    acc[r][c] = fmaf(ar[r], br[c], acc[r][c]);
        }
        __syncthreads();
    }
#pragma unroll
    for (int r = 0; r < 4; r++) {
        int i = i0 + ty * 4 + r;
#pragma unroll
        for (int c = 0; c < 4; c++) {
            int j = j0 + tx * 4 + c;
            float Kv = (i == j) ? 0.0f : __expf(acc[r][c] * 0.0625f);
            float* outb = out + (size_t)bb * NP1 * NP1;
            outb[(size_t)i * NP1 + j] = Kv;
            if (tj > ti) outb[(size_t)j * NP1 + i] = Kv;
        }
    }
}

// Persistent Sinkhorn, 128 KB fp8 K-shard in LDS — byte-identical to R13.
__global__ __launch_bounds__(1024) void sink_persist(const unsigned char* __restrict__ K8,
                                                     float* __restrict__ avec,
                                                     float* __restrict__ bvec,
                                                     int* __restrict__ bar,
                                                     float* __restrict__ psum,
                                                     const float* __restrict__ alpha) {
    int blk   = blockIdx.x;
    int batch = blk & 7;           // XCD id under round-robin dispatch
    int rb    = blk >> 3;
    int tid   = threadIdx.x;
    int seg   = tid & 15;
    int row   = tid >> 4;          // row within the 64-row shard
    int grow  = rb * 64 + row;     // global row

    __shared__ __align__(16) unsigned char Ks[64 * 2048];   // 128 KB fp8 shard
    __shared__ float xs[16 * 132];                          // padded x stage
    __shared__ float wsum[16];
    __shared__ float stot;

    {
        const int4* gsrc = (const int4*)(K8 + ((size_t)batch * NN + (size_t)rb * 64) * NN);
#pragma unroll
        for (int q = 0; q < 8; q++) {
            int idx = q * 1024 + tid;
            int4 v = gsrc[idx];
            int g = idx * 16;
            int r_ = g >> 11, bir = g & 2047;
            *(int4*)&Ks[r_ * 2048 + (bir ^ (((bir >> 7) & 7) << 4))] = v;
        }
    }   // first pass's __syncthreads() covers this staging

    float* av = avec + (size_t)batch * VSTR;
    float* bv = bvec + (size_t)batch * VSTR;
    int*   gbar = bar + batch * GRP;
    float E    = __expf(alpha[0]);
    float binA = 0.f, binB = 1.0f;
    float S_in = 2048.0f;
    int   ep   = 0;
    const float4* xp4 = (const float4*)(xs + seg * 132);
    const int kbase = row * 2048;
    const int sb    = seg * 128;
    const int sx    = (seg & 7) << 4;

#define MAC16(KI, ACC)                                                          \
    {                                                                           \
        int4 kv = *(const int4*)&Ks[kbase + ((sb + (KI) * 16) ^ sx)];           \
        float4 xa = xp4[(KI) * 4 + 0], xb = xp4[(KI) * 4 + 1];                  \
        float4 xc = xp4[(KI) * 4 + 2], xd = xp4[(KI) * 4 + 3];                  \
        f32x2 p0 = __builtin_amdgcn_cvt_pk_f32_fp8(kv.x, false);                \
        f32x2 p1 = __builtin_amdgcn_cvt_pk_f32_fp8(kv.x, true);                 \
        f32x2 p2 = __builtin_amdgcn_cvt_pk_f32_fp8(kv.y, false);                \
        f32x2 p3 = __builtin_amdgcn_cvt_pk_f32_fp8(kv.y, true);                 \
        f32x2 p4 = __builtin_amdgcn_cvt_pk_f32_fp8(kv.z, false);                \
        f32x2 p5 = __builtin_amdgcn_cvt_pk_f32_fp8(kv.z, true);                 \
        f32x2 p6 = __builtin_amdgcn_cvt_pk_f32_fp8(kv.w, false);                \
        f32x2 p7 = __builtin_amdgcn_cvt_pk_f32_fp8(kv.w, true);                 \
        ACC = fmaf(p0.x, xa.x, ACC); ACC = fmaf(p0.y, xa.y, ACC);               \
        ACC = fmaf(p1.x, xa.z, ACC); ACC = fmaf(p1.y, xa.w, ACC);               \
        ACC = fmaf(p2.x, xb.x, ACC); ACC = fmaf(p2.y, xb.y, ACC);               \
        ACC = fmaf(p3.x, xb.z, ACC); ACC = fmaf(p3.y, xb.w, ACC);               \
        ACC = fmaf(p4.x, xc.x, ACC); ACC = fmaf(p4.y, xc.y, ACC);               \
        ACC = fmaf(p5.x, xc.z, ACC); ACC = fmaf(p5.y, xc.w, ACC);               \
        ACC = fmaf(p6.x, xd.x, ACC); ACC = fmaf(p6.y, xd.y, ACC);               \
        ACC = fmaf(p7.x, xd.z, ACC); ACC = fmaf(p7.y, xd.w, ACC);               \
    }

#define SINK_PASS(XIN, XOUT, BIN_IN, BIN_OUT, P, LAST)                          \
    {                                                                           \
        {                                                                       \
            float2 v = ((const float2*)(XIN))[tid];                             \
            int j = tid * 2;                                                    \
            float* d = xs + ((j >> 7) * 132 + (j & 127));                       \
            d[0] = v.x; d[1] = v.y;                                             \
        }                                                                       \
        __syncthreads();                                                        \
        float dot0 = 0.f, dot1 = 0.f;                                           \
        MAC16(0, dot0) MAC16(1, dot1) MAC16(2, dot0) MAC16(3, dot1)             \
        MAC16(4, dot0) MAC16(5, dot1) MAC16(6, dot0) MAC16(7, dot1)             \
        float dot = dot0 + dot1;                                                \
        dot += __shfl_xor(dot, 1);                                              \
        dot += __shfl_xor(dot, 2);                                              \
        dot += __shfl_xor(dot, 4);                                              \
        dot += __shfl_xor(dot, 8);                                              \
        float val = (1.0f / 4096.0f) / (dot + E * (BIN_IN));                    \
        BIN_OUT = 0.5f / (E * (S_in + (BIN_IN)));                               \
        float ys = val;                                                         \
        ys += __shfl_xor(ys, 16);                                               \
        ys += __shfl_xor(ys, 32);                                               \
        if ((tid & 15) == 0) (XOUT)[grow] = val;                                \
        if ((tid & 63) == 0) wsum[tid >> 6] = ys;                               \
        __syncthreads();                                                        \
        if (!(LAST)) {                                                          \
            ep++;                                                               \
            float* pp = psum + (((P) & 1) * BN + batch) * GRP;                  \
            if (tid == 0) {                                                     \
                float s = 0.f;                                                  \
                _Pragma("unroll")                                               \
                for (int w = 0; w < 16; w++) s += wsum[w];                      \
                __hip_atomic_store(&pp[rb], s, __ATOMIC_RELAXED,                \
                                   __HIP_MEMORY_SCOPE_AGENT);                   \
                __builtin_amdgcn_fence(__ATOMIC_RELEASE, "agent");              \
                __hip_atomic_store(&gbar[rb], ep, __ATOMIC_RELAXED,             \
                                   __HIP_MEMORY_SCOPE_AGENT);                   \
            }                                                                   \
            if (tid < GRP) {                                                    \
                while (__hip_atomic_load(&gbar[tid], __ATOMIC_RELAXED,          \
                                         __HIP_MEMORY_SCOPE_AGENT) < ep)        \
                    __builtin_amdgcn_s_sleep(1);                                \
            }                                                                   \
            if (tid < 64) {                                                     \
                __builtin_amdgcn_fence(__ATOMIC_ACQUIRE, "agent");              \
                float ps = 0.f;                                                 \
                if (tid < GRP)                                                  \
                    ps = __hip_atomic_load(&pp[tid], __ATOMIC_RELAXED,          \
                                           __HIP_MEMORY_SCOPE_AGENT);           \
                ps += __shfl_xor(ps, 1);                                        \
                ps += __shfl_xor(ps, 2);                                        \
                ps += __shfl_xor(ps, 4);                                        \
                ps += __shfl_xor(ps, 8);                                        \
                ps += __shfl_xor(ps, 16);                                       \
                if (tid == 0) stot = ps;                                        \
            }                                                                   \
            __syncthreads();                                                    \
            S_in = stot;                                                        \
        }                                                                       \
    }

    for (int it2 = 0; it2 < NITER; it2++) {
        int p = 2 * it2 + 1;
        SINK_PASS(bv, av, binB, binA, p, false);
        SINK_PASS(av, bv, binA, binB, p + 1, (it2 == NITER - 1));
    }
#undef SINK_PASS
#undef MAC16

    if (tid == 0) { av[NN] = binA; bv[NN] = binB; }
}

// fp32 fallback pass (K in d_out, stride NP1) for ws-too-small case.
__global__ __launch_bounds__(256) void sink_pass_f32(const float* __restrict__ K,
                                                     const float* __restrict__ xin,
                                                     float* __restrict__ xout,
                                                     const float* __restrict__ sum_in,
                                                     float* __restrict__ sum_out,
                                                     const float* __restrict__ alpha) {
    int bb = blockIdx.y;
    int i0 = blockIdx.x * 16;
    __shared__ float xsl[NN];
    __shared__ float rowa[16];
    const float* xinb = xin + (size_t)bb * VSTR;
    int t = threadIdx.x;
    for (int j = t; j < NN; j += 256) xsl[j] = xinb[j];
    __syncthreads();
    float E  = __expf(alpha[0]);
    float xN = xinb[NN];
    int wave = t >> 6, lane = t & 63;
    const float* Kb = K + (size_t)bb * NP1 * NP1;
    for (int r = wave; r < 16; r += 4) {
        int i = i0 + r;
        const float* rowp = Kb + (size_t)i * NP1;
        float acc = 0.f;
        for (int j = lane; j < NN; j += 64) acc = fmaf(rowp[j], xsl[j], acc);
#pragma unroll
        for (int off = 32; off >= 1; off >>= 1) acc += __shfl_xor(acc, off);
        if (lane == 0) {
            float v = (1.0f / 4096.0f) / (acc + E * xN);
            xout[(size_t)bb * VSTR + i] = v;
            rowa[r] = v;
        }
    }
    __syncthreads();
    if (t == 0) {
        float s = 0.f;
#pragma unroll
        for (int r = 0; r < 16; r++) s += rowa[r];
        atomicAdd(sum_out + bb, s);
        if (blockIdx.x == 0) xout[(size_t)bb * VSTR + NN] = 0.5f / (E * (sum_in[bb] + xN));
    }
}

// out[i,j] = K*a_i*b_j*4096*cost (i,j<N), bins use E. FP8: K from K8; else in-place.
template <bool FP8>
__global__ __launch_bounds__(256) void final_kernel(float* __restrict__ out,
                                                    const unsigned char* __restrict__ K8,
                                                    const float* __restrict__ avec,
                                                    const float* __restrict__ bvec,
                                                    const float* __restrict__ pos,
                                                    const float* __restrict__ alpha) {
    int bb = blockIdx.y;
    int i0 = blockIdx.x * 16;
    __shared__ float as_[16], ys[16], xs2[16];
    int t = threadIdx.x;
    if (t < 16) {
        int i = i0 + t;
        as_[t] = (i < NP1) ? avec[(size_t)bb * VSTR + i] : 0.f;
        if (i < NN) {
            ys[t]  = pos[((size_t)bb * NN + i) * 2 + 0];
            xs2[t] = pos[((size_t)bb * NN + i) * 2 + 1];
        } else {
            ys[t] = 1e9f; xs2[t] = 1e9f;
        }
    }
    __syncthreads();
    float E = __expf(alpha[0]);
    float* outb = out + (size_t)bb * NP1 * NP1;
    const unsigned char* K8b = K8 + (size_t)bb * NN * NN;
    for (int j = t; j < NP1; j += 256) {
        float bj = bvec[(size_t)bb * VSTR + j];
        bool jin = (j < NN);
        float yj = 0.f, xj = 0.f;
        if (jin) {
            yj = pos[((size_t)bb * NN + j) * 2 + 0];
            xj = pos[((size_t)bb * NN + j) * 2 + 1];
        }
#pragma unroll 1
        for (int r = 0; r < 16; r++) {
            int i = i0 + r;
            if (i >= NP1) break;
            size_t idx = (size_t)i * NP1 + j;
            float v;
            if (i < NN && jin) {
                float Kv;
                if constexpr (FP8)
                    Kv = __builtin_amdgcn_cvt_f32_fp8((int)K8b[(size_t)i * NN + j], 0);
                else
                    Kv = outb[idx];
                bool c = (fabsf(ys[r] - yj) <= 0.1f) && (fabsf(xs2[r] - xj) <= 0.1f);
                v = c ? Kv * as_[r] * bj * 4096.0f : 0.0f;
            } else {
                v = E * as_[r] * bj * 4096.0f;
            }
            outb[idx] = v;
        }
    }
}

extern "C" void kernel_launch(void* const* d_in, const int* in_sizes, int n_in,
                              void* d_out, int out_size, void* d_ws, size_t ws_size,
                              hipStream_t stream) {
    const float* F     = (const float*)d_in[0];  // (B, D, N)
    const float* pos   = (const float*)d_in[1];  // (B, N, 2)
    const float* alpha = (const float*)d_in[3];  // (1,)
    float* out = (float*)d_out;
    float* ws  = (float*)d_ws;

    float* avec = ws;
    float* bvec = ws + BN * VSTR;
    float* sums = ws + 2 * BN * VSTR;                 // 41*BN floats (fallback path)
    int*   bar  = (int*)(sums + 41 * BN);             // BN x GRP arrival slots
    float* psum = (float*)(bar + BN * GRP);           // 2 x BN x GRP partial sums
    unsigned char* K8 = (unsigned char*)(psum + 2 * BN * GRP);  // 33.5 MB fp8

    size_t need = (size_t)(2 * BN * VSTR + 41 * BN + 3 * BN * GRP) * 4
                + (size_t)BN * NN * NN;
    bool fp8 = (ws_size >= need);

    hipLaunchKernelGGL(init_kernel, dim3(64), dim3(256), 0, stream, bvec, BN * VSTR,
                       sums, bar);

    if (fp8) {
        hipLaunchKernelGGL(build_k3, dim3(16, 16, BN), dim3(256), 0, stream, F, K8);
        const unsigned char* Kp = K8;
        float* ap = avec; float* bp = bvec; int* brp = bar; float* pp = psum;
        const float* alp = alpha;
        void* params[6] = {(void*)&Kp, (void*)&ap, (void*)&bp, (void*)&brp,
                           (void*)&pp, (void*)&alp};
        hipLaunchCooperativeKernel((const void*)sink_persist, dim3(NBLK), dim3(1024),
                                   params, 0, stream);
        hipLaunchKernelGGL((final_kernel<true>), dim3((NP1 + 15) / 16, BN), dim3(256), 0,
                           stream, out, K8, avec, bvec, pos, alpha);
    } else {
        hipLaunchKernelGGL(build_k_f32, dim3(32, 32, BN), dim3(256), 0, stream, F, out);
        const float* xin = bvec;
        float* xout = avec;
        for (int p = 1; p <= 2 * NITER; p++) {
            hipLaunchKernelGGL(sink_pass_f32, dim3(NN / 16, BN), dim3(256), 0, stream,
                               out, xin, xout, sums + (p - 1) * BN, sums + p * BN, alpha);
            float* tmp = (float*)xin; xin = xout; xout = tmp;
        }
        hipLaunchKernelGGL((final_kernel<false>), dim3((NP1 + 15) / 16, BN), dim3(256), 0,
                           stream, out, K8, avec, bvec, pos, alpha);
    }
}

// Round 15
// 360.061 us; speedup vs baseline: 1.7929x; 1.4316x over previous
//
#include <hip/hip_runtime.h>
#include <math.h>

#define BN    8
#define NN    2048
#define NP1   2049
#define VSTR  2056   // padded a/b vector stride (floats), 16B-aligned rows
#define DD    256
#define NITER 20
#define NBLK  256    // persistent grid size, 1 block/CU
#define GRP   32     // blocks per batch (independent barrier group)

typedef float f32x2 __attribute__((ext_vector_type(2)));
typedef float f32x4_t __attribute__((ext_vector_type(4)));
typedef short short8 __attribute__((ext_vector_type(8)));

// ws layout: a[BN*VSTR] f32 | b[BN*VSTR] f32 | sums[41*BN] f32 | bar[BN*GRP] i32 |
//            psum[2*BN*GRP] f32 (unused) | K8[BN*NN*NN] fp8

__global__ void init_kernel(float* __restrict__ bvec, int nb, float* __restrict__ sums,
                            int* __restrict__ bar) {
    int tid = blockIdx.x * blockDim.x + threadIdx.x;
    int stride = gridDim.x * blockDim.x;
    for (int i = tid; i < nb; i += stride) bvec[i] = 1.0f;            // v0 = 0 -> b = 1
    for (int i = tid; i < 41 * BN; i += stride) sums[i] = (i < BN) ? (float)NN : 0.0f;
    if (tid < BN * GRP) bar[tid] = 0;
}

__device__ __forceinline__ unsigned short f2bf(float f) {
    unsigned u = __builtin_bit_cast(unsigned, f);
    return (unsigned short)((u + 0x7fffu + ((u >> 16) & 1u)) >> 16);   // RNE
}

// build_k v3: MFMA bf16 (identical to R14). K = exp(F^T F / 16), diag=0, fp8 out.
__global__ __launch_bounds__(256) void build_k3(const float* __restrict__ F,
                                                unsigned char* __restrict__ K8) {
    int ti = blockIdx.x, tj = blockIdx.y, bb = blockIdx.z;
    int i0 = ti * 128, j0 = tj * 128;
    const float* Fb = F + (size_t)bb * DD * NN;

    __shared__ __align__(16) unsigned char Ab[128 * 80];   // [x][k] bf16, 80B rows
    __shared__ __align__(16) unsigned char Bb[128 * 80];
    __shared__ __align__(4)  unsigned char Cm[128 * 132];  // col-major fp8 [c][i]

    int t = threadIdx.x;
    int w = t >> 6, l = t & 63;
    int wr = w >> 1, wc = w & 1;           // wave grid 2x2 -> 64x64 per wave
    int g = l >> 4, c16 = l & 15;

    f32x4_t acc[4][4];
#pragma unroll
    for (int r = 0; r < 4; r++)
#pragma unroll
        for (int c = 0; c < 4; c++) acc[r][c] = (f32x4_t){0.f, 0.f, 0.f, 0.f};

    for (int k0 = 0; k0 < DD; k0 += 32) {
#pragma unroll
        for (int q = 0; q < 4; q++) {
            int idx = q * 256 + t;
            int x = idx & 127, k4 = (idx >> 7) * 4;
            unsigned long long pa = 0, pb = 0;
#pragma unroll
            for (int e = 0; e < 4; e++) {
                const float* rowp = Fb + (size_t)(k0 + k4 + e) * NN;
                pa |= (unsigned long long)f2bf(rowp[i0 + x]) << (16 * e);
                pb |= (unsigned long long)f2bf(rowp[j0 + x]) << (16 * e);
            }
            *(unsigned long long*)(Ab + x * 80 + k4 * 2) = pa;
            *(unsigned long long*)(Bb + x * 80 + k4 * 2) = pb;
        }
        __syncthreads();

        short8 af[4], bf_[4];
#pragma unroll
        for (int rf = 0; rf < 4; rf++)
            af[rf] = *(const short8*)(Ab + (wr * 64 + rf * 16 + c16) * 80 + g * 16);
#pragma unroll
        for (int cf = 0; cf < 4; cf++)
            bf_[cf] = *(const short8*)(Bb + (wc * 64 + cf * 16 + c16) * 80 + g * 16);
#pragma unroll
        for (int rf = 0; rf < 4; rf++)
#pragma unroll
            for (int cf = 0; cf < 4; cf++)
                acc[rf][cf] = __builtin_amdgcn_mfma_f32_16x16x32_bf16(
                    af[rf], bf_[cf], acc[rf][cf], 0, 0, 0);
        __syncthreads();
    }

#pragma unroll
    for (int rf = 0; rf < 4; rf++) {
#pragma unroll
        for (int cf = 0; cf < 4; cf++) {
            int ib = wr * 64 + rf * 16 + g * 4;
            int jl = wc * 64 + cf * 16 + c16;
            float v[4];
#pragma unroll
            for (int r = 0; r < 4; r++) {
                float e = __expf(acc[rf][cf][r] * 0.0625f);   // 1/sqrt(256)
                if (i0 + ib + r == j0 + jl) e = 0.0f;
                v[r] = e;
            }
            unsigned wd = __builtin_amdgcn_cvt_pk_fp8_f32(v[0], v[1], 0, false);
            wd = __builtin_amdgcn_cvt_pk_fp8_f32(v[2], v[3], wd, true);
            *(unsigned*)(Cm + jl * 132 + ib) = wd;
        }
    }
    __syncthreads();

    unsigned char* K8b = K8 + (size_t)bb * NN * NN;
    int il = t >> 1, hh = t & 1;
    unsigned wrow[16];
#pragma unroll
    for (int cq = 0; cq < 16; cq++) {
        int cb = hh * 64 + cq * 4;
        unsigned b0 = Cm[(cb + 0) * 132 + il];
        unsigned b1 = Cm[(cb + 1) * 132 + il];
        unsigned b2 = Cm[(cb + 2) * 132 + il];
        unsigned b3 = Cm[(cb + 3) * 132 + il];
        wrow[cq] = b0 | (b1 << 8) | (b2 << 16) | (b3 << 24);
    }
    uint4* dst = (uint4*)(K8b + (size_t)(i0 + il) * NN + j0 + hh * 64);
#pragma unroll
    for (int qq = 0; qq < 4; qq++) {
        uint4 u; u.x = wrow[qq * 4]; u.y = wrow[qq * 4 + 1];
        u.z = wrow[qq * 4 + 2]; u.w = wrow[qq * 4 + 3];
        dst[qq] = u;
    }
}

// fp32 fallback build (writes into out, stride NP1). Symmetric-half as before.
__global__ __launch_bounds__(256) void build_k_f32(const float* __restrict__ F,
                                                   float* __restrict__ out) {
    int ti = blockIdx.x, tj = blockIdx.y, bb = blockIdx.z;
    if (tj < ti) return;
    __shared__ float As[32][64];
    __shared__ float Bs[32][64];
    int t  = threadIdx.x;
    int tx = t & 15, ty = t >> 4;
    float acc[4][4] = {};
    const float* Fb = F + (size_t)bb * DD * NN;
    int i0 = ti * 64, j0 = tj * 64;
    for (int k0 = 0; k0 < DD; k0 += 32) {
#pragma unroll
        for (int v = 0; v < 2; v++) {
            int f = t + 256 * v;
            int row = f >> 4, c4 = (f & 15) * 4;
            *(float4*)&As[row][c4] = *(const float4*)&Fb[(size_t)(k0 + row) * NN + i0 + c4];
            *(float4*)&Bs[row][c4] = *(const float4*)&Fb[(size_t)(k0 + row) * NN + j0 + c4];
        }
        __syncthreads();
#pragma unroll
        for (int k = 0; k < 32; k++) {
            float4 av = *(float4*)&As[k][ty * 4];
            float4 bv = *(float4*)&Bs[k][tx * 4];
            float ar[4] = {av.x, av.y, av.z, av.w};
            float br[4] = {bv.x, bv.y, bv.z, bv.w};
#pragma unroll
            for (int r = 0; r < 4; r++)
#pragma unroll
                for (int c = 0; c < 4; c++)
                    acc[r][c] = fmaf(ar[r], br[c], acc[r][c]);
        }
        __syncthreads();
    }
#pragma unroll
    for (int r = 0; r < 4; r++) {
        int i = i0 + ty * 4 + r;
#pragma unroll
        for (int c = 0; c < 4; c++) {
            int j = j0 + tx * 4 + c;
            float Kv = (i == j) ? 0.0f : __expf(acc[r][c] * 0.0625f);
            float* outb = out + (size_t)bb * NP1 * NP1;
            outb[(size_t)i * NP1 + j] = Kv;
            if (tj > ti) outb[(size_t)j * NP1 + i] = Kv;
        }
    }
}

// Persistent Sinkhorn, 128 KB fp8 K-shard in LDS. R14 post-mortem: agent-scope
// release/acquire FENCES compile to per-pass L2 maintenance (buffer_wbl2 /
// buffer_inv) on multi-XCD gfx950 — 512 L2 ops/pass, invariant to flag layout
// (explains 3 neutral sync rounds). This round: fence-FREE exchange — the x
// values themselves are agent-scope RELAXED ATOMICS (sc1: bypass L1/L2, read/
// write the coherence point directly), ordered by __syncthreads()'s vmcnt(0)
// drain. Bin-sum exchange DELETED: S(x_in) computed locally from the staged x.
__global__ __launch_bounds__(1024) void sink_persist(const unsigned char* __restrict__ K8,
                                                     float* __restrict__ avec,
                                                     float* __restrict__ bvec,
                                                     int* __restrict__ bar,
                                                     const float* __restrict__ alpha) {
    int blk   = blockIdx.x;
    int batch = blk & 7;           // XCD id under round-robin dispatch
    int rb    = blk >> 3;
    int tid   = threadIdx.x;
    int seg   = tid & 15;
    int row   = tid >> 4;          // row within the 64-row shard
    int grow  = rb * 64 + row;     // global row

    __shared__ __align__(16) unsigned char Ks[64 * 2048];   // 128 KB fp8 shard
    __shared__ float xs[16 * 132];                          // padded x stage
    __shared__ float wsum[16];

    {
        const int4* gsrc = (const int4*)(K8 + ((size_t)batch * NN + (size_t)rb * 64) * NN);
#pragma unroll
        for (int q = 0; q < 8; q++) {
            int idx = q * 1024 + tid;
            int4 v = gsrc[idx];
            int g = idx * 16;
            int r_ = g >> 11, bir = g & 2047;
            *(int4*)&Ks[r_ * 2048 + (bir ^ (((bir >> 7) & 7) << 4))] = v;
        }
    }   // first pass's __syncthreads() covers this staging

    float* av = avec + (size_t)batch * VSTR;
    float* bv = bvec + (size_t)batch * VSTR;
    int*   gbar = bar + batch * GRP;
    float E    = __expf(alpha[0]);
    float binA = 0.f, binB = 1.0f;
    int   ep   = 0;
    const float4* xp4 = (const float4*)(xs + seg * 132);
    const int kbase = row * 2048;
    const int sb    = seg * 128;
    const int sx    = (seg & 7) << 4;

#define MAC16(KI, ACC)                                                          \
    {                                                                           \
        int4 kv = *(const int4*)&Ks[kbase + ((sb + (KI) * 16) ^ sx)];           \
        float4 xa = xp4[(KI) * 4 + 0], xb = xp4[(KI) * 4 + 1];                  \
        float4 xc = xp4[(KI) * 4 + 2], xd = xp4[(KI) * 4 + 3];                  \
        f32x2 p0 = __builtin_amdgcn_cvt_pk_f32_fp8(kv.x, false);                \
        f32x2 p1 = __builtin_amdgcn_cvt_pk_f32_fp8(kv.x, true);                 \
        f32x2 p2 = __builtin_amdgcn_cvt_pk_f32_fp8(kv.y, false);                \
        f32x2 p3 = __builtin_amdgcn_cvt_pk_f32_fp8(kv.y, true);                 \
        f32x2 p4 = __builtin_amdgcn_cvt_pk_f32_fp8(kv.z, false);                \
        f32x2 p5 = __builtin_amdgcn_cvt_pk_f32_fp8(kv.z, true);                 \
        f32x2 p6 = __builtin_amdgcn_cvt_pk_f32_fp8(kv.w, false);                \
        f32x2 p7 = __builtin_amdgcn_cvt_pk_f32_fp8(kv.w, true);                 \
        ACC = fmaf(p0.x, xa.x, ACC); ACC = fmaf(p0.y, xa.y, ACC);               \
        ACC = fmaf(p1.x, xa.z, ACC); ACC = fmaf(p1.y, xa.w, ACC);               \
        ACC = fmaf(p2.x, xb.x, ACC); ACC = fmaf(p2.y, xb.y, ACC);               \
        ACC = fmaf(p3.x, xb.z, ACC); ACC = fmaf(p3.y, xb.w, ACC);               \
        ACC = fmaf(p4.x, xc.x, ACC); ACC = fmaf(p4.y, xc.y, ACC);               \
        ACC = fmaf(p5.x, xc.z, ACC); ACC = fmaf(p5.y, xc.w, ACC);               \
        ACC = fmaf(p6.x, xd.x, ACC); ACC = fmaf(p6.y, xd.y, ACC);               \
        ACC = fmaf(p7.x, xd.z, ACC); ACC = fmaf(p7.y, xd.w, ACC);               \
    }

#define SINK_PASS(XIN, XOUT, BIN_IN, BIN_OUT, LAST)                             \
    {                                                                           \
        float sv;                                                               \
        {   /* stage XIN via sc1 atomic loads (coherence-point reads) */        \
            float v0 = __hip_atomic_load((XIN) + 2 * tid, __ATOMIC_RELAXED,     \
                                         __HIP_MEMORY_SCOPE_AGENT);             \
            float v1 = __hip_atomic_load((XIN) + 2 * tid + 1, __ATOMIC_RELAXED, \
                                         __HIP_MEMORY_SCOPE_AGENT);             \
            int j = tid * 2;                                                    \
            float* d = xs + ((j >> 7) * 132 + (j & 127));                       \
            d[0] = v0; d[1] = v1;                                               \
            sv = v0 + v1;                                                       \
        }                                                                       \
        sv += __shfl_xor(sv, 1);  sv += __shfl_xor(sv, 2);                      \
        sv += __shfl_xor(sv, 4);  sv += __shfl_xor(sv, 8);                      \
        sv += __shfl_xor(sv, 16); sv += __shfl_xor(sv, 32);                     \
        if ((tid & 63) == 0) wsum[tid >> 6] = sv;                               \
        __syncthreads();                                                        \
        float S_cur = 0.f;                                                      \
        _Pragma("unroll")                                                       \
        for (int w2 = 0; w2 < 16; w2++) S_cur += wsum[w2];                      \
        float dot0 = 0.f, dot1 = 0.f;                                           \
        MAC16(0, dot0) MAC16(1, dot1) MAC16(2, dot0) MAC16(3, dot1)             \
        MAC16(4, dot0) MAC16(5, dot1) MAC16(6, dot0) MAC16(7, dot1)             \
        float dot = dot0 + dot1;                                                \
        dot += __shfl_xor(dot, 1);                                              \
        dot += __shfl_xor(dot, 2);                                              \
        dot += __shfl_xor(dot, 4);                                              \
        dot += __shfl_xor(dot, 8);                                              \
        float val = (1.0f / 4096.0f) / (dot + E * (BIN_IN));                    \
        BIN_OUT = 0.5f / (E * (S_cur + (BIN_IN)));                              \
        if ((tid & 15) == 0)                                                    \
            __hip_atomic_store(&(XOUT)[grow], val, __ATOMIC_RELAXED,            \
                               __HIP_MEMORY_SCOPE_AGENT);                       \
        __syncthreads();   /* vmcnt(0) drain: val stores complete (sc1) */      \
        if (!(LAST)) {                                                          \
            ep++;                                                               \
            if (tid == 0)                                                       \
                __hip_atomic_store(&gbar[rb], ep, __ATOMIC_RELAXED,             \
                                   __HIP_MEMORY_SCOPE_AGENT);                   \
            if (tid < GRP) {                                                    \
                while (__hip_atomic_load(&gbar[tid], __ATOMIC_RELAXED,          \
                                         __HIP_MEMORY_SCOPE_AGENT) < ep)        \
                    __builtin_amdgcn_s_sleep(1);                                \
            }                                                                   \
            __syncthreads();                                                    \
        }                                                                       \
    }

    for (int it2 = 0; it2 < NITER; it2++) {
        SINK_PASS(bv, av, binB, binA, false);
        SINK_PASS(av, bv, binA, binB, (it2 == NITER - 1));
    }
#undef SINK_PASS
#undef MAC16

    if (tid == 0) { av[NN] = binA; bv[NN] = binB; }
}

// fp32 fallback pass (K in d_out, stride NP1) for ws-too-small case.
__global__ __launch_bounds__(256) void sink_pass_f32(const float* __restrict__ K,
                                                     const float* __restrict__ xin,
                                                     float* __restrict__ xout,
                                                     const float* __restrict__ sum_in,
                                                     float* __restrict__ sum_out,
                                                     const float* __restrict__ alpha) {
    int bb = blockIdx.y;
    int i0 = blockIdx.x * 16;
    __shared__ float xsl[NN];
    __shared__ float rowa[16];
    const float* xinb = xin + (size_t)bb * VSTR;
    int t = threadIdx.x;
    for (int j = t; j < NN; j += 256) xsl[j] = xinb[j];
    __syncthreads();
    float E  = __expf(alpha[0]);
    float xN = xinb[NN];
    int wave = t >> 6, lane = t & 63;
    const float* Kb = K + (size_t)bb * NP1 * NP1;
    for (int r = wave; r < 16; r += 4) {
        int i = i0 + r;
        const float* rowp = Kb + (size_t)i * NP1;
        float acc = 0.f;
        for (int j = lane; j < NN; j += 64) acc = fmaf(rowp[j], xsl[j], acc);
#pragma unroll
        for (int off = 32; off >= 1; off >>= 1) acc += __shfl_xor(acc, off);
        if (lane == 0) {
            float v = (1.0f / 4096.0f) / (acc + E * xN);
            xout[(size_t)bb * VSTR + i] = v;
            rowa[r] = v;
        }
    }
    __syncthreads();
    if (t == 0) {
        float s = 0.f;
#pragma unroll
        for (int r = 0; r < 16; r++) s += rowa[r];
        atomicAdd(sum_out + bb, s);
        if (blockIdx.x == 0) xout[(size_t)bb * VSTR + NN] = 0.5f / (E * (sum_in[bb] + xN));
    }
}

// out[i,j] = K*a_i*b_j*4096*cost (i,j<N), bins use E. FP8: K from K8; else in-place.
template <bool FP8>
__global__ __launch_bounds__(256) void final_kernel(float* __restrict__ out,
                                                    const unsigned char* __restrict__ K8,
                                                    const float* __restrict__ avec,
                                                    const float* __restrict__ bvec,
                                                    const float* __restrict__ pos,
                                                    const float* __restrict__ alpha) {
    int bb = blockIdx.y;
    int i0 = blockIdx.x * 16;
    __shared__ float as_[16], ys[16], xs2[16];
    int t = threadIdx.x;
    if (t < 16) {
        int i = i0 + t;
        as_[t] = (i < NP1) ? avec[(size_t)bb * VSTR + i] : 0.f;
        if (i < NN) {
            ys[t]  = pos[((size_t)bb * NN + i) * 2 + 0];
            xs2[t] = pos[((size_t)bb * NN + i) * 2 + 1];
        } else {
            ys[t] = 1e9f; xs2[t] = 1e9f;
        }
    }
    __syncthreads();
    float E = __expf(alpha[0]);
    float* outb = out + (size_t)bb * NP1 * NP1;
    const unsigned char* K8b = K8 + (size_t)bb * NN * NN;
    for (int j = t; j < NP1; j += 256) {
        float bj = bvec[(size_t)bb * VSTR + j];
        bool jin = (j < NN);
        float yj = 0.f, xj = 0.f;
        if (jin) {
            yj = pos[((size_t)bb * NN + j) * 2 + 0];
            xj = pos[((size_t)bb * NN + j) * 2 + 1];
        }
#pragma unroll 1
        for (int r = 0; r < 16; r++) {
            int i = i0 + r;
            if (i >= NP1) break;
            size_t idx = (size_t)i * NP1 + j;
            float v;
            if (i < NN && jin) {
                float Kv;
                if constexpr (FP8)
                    Kv = __builtin_amdgcn_cvt_f32_fp8((int)K8b[(size_t)i * NN + j], 0);
                else
                    Kv = outb[idx];
                bool c = (fabsf(ys[r] - yj) <= 0.1f) && (fabsf(xs2[r] - xj) <= 0.1f);
                v = c ? Kv * as_[r] * bj * 4096.0f : 0.0f;
            } else {
                v = E * as_[r] * bj * 4096.0f;
            }
            outb[idx] = v;
        }
    }
}

extern "C" void kernel_launch(void* const* d_in, const int* in_sizes, int n_in,
                              void* d_out, int out_size, void* d_ws, size_t ws_size,
                              hipStream_t stream) {
    const float* F     = (const float*)d_in[0];  // (B, D, N)
    const float* pos   = (const float*)d_in[1];  // (B, N, 2)
    const float* alpha = (const float*)d_in[3];  // (1,)
    float* out = (float*)d_out;
    float* ws  = (float*)d_ws;

    float* avec = ws;
    float* bvec = ws + BN * VSTR;
    float* sums = ws + 2 * BN * VSTR;                 // 41*BN floats (fallback path)
    int*   bar  = (int*)(sums + 41 * BN);             // BN x GRP arrival slots
    float* psum = (float*)(bar + BN * GRP);           // kept for layout stability
    unsigned char* K8 = (unsigned char*)(psum + 2 * BN * GRP);  // 33.5 MB fp8

    size_t need = (size_t)(2 * BN * VSTR + 41 * BN + 3 * BN * GRP) * 4
                + (size_t)BN * NN * NN;
    bool fp8 = (ws_size >= need);

    hipLaunchKernelGGL(init_kernel, dim3(64), dim3(256), 0, stream, bvec, BN * VSTR,
                       sums, bar);

    if (fp8) {
        hipLaunchKernelGGL(build_k3, dim3(16, 16, BN), dim3(256), 0, stream, F, K8);
        const unsigned char* Kp = K8;
        float* ap = avec; float* bp = bvec; int* brp = bar;
        const float* alp = alpha;
        void* params[5] = {(void*)&Kp, (void*)&ap, (void*)&bp, (void*)&brp,
                           (void*)&alp};
        hipLaunchCooperativeKernel((const void*)sink_persist, dim3(NBLK), dim3(1024),
                                   params, 0, stream);
        hipLaunchKernelGGL((final_kernel<true>), dim3((NP1 + 15) / 16, BN), dim3(256), 0,
                           stream, out, K8, avec, bvec, pos, alpha);
    } else {
        hipLaunchKernelGGL(build_k_f32, dim3(32, 32, BN), dim3(256), 0, stream, F, out);
        const float* xin = bvec;
        float* xout = avec;
        for (int p = 1; p <= 2 * NITER; p++) {
            hipLaunchKernelGGL(sink_pass_f32, dim3(NN / 16, BN), dim3(256), 0, stream,
                               out, xin, xout, sums + (p - 1) * BN, sums + p * BN, alpha);
            float* tmp = (float*)xin; xin = xout; xout = tmp;
        }
        hipLaunchKernelGGL((final_kernel<false>), dim3((NP1 + 15) / 16, BN), dim3(256), 0,
                           stream, out, K8, avec, bvec, pos, alpha);
    }
}